// Round 8
// baseline (1732.651 us; speedup 1.0000x reference)
//
#include <hip/hip_runtime.h>

#define T_STEPS 1000
#define N_IN    700
#define N_HID   4096
#define N_OUT   20
#define NBLK    256   // main-loop blocks: 1 wave, 16 neurons each
#define NPB     16    // neurons per block

typedef unsigned int u32x4 __attribute__((ext_vector_type(4)));
typedef unsigned int u32x2 __attribute__((ext_vector_type(2)));

// 4B device-coherent record ops; waitcnt INSIDE asm (no live in-flight regs)
__device__ __forceinline__ unsigned load_rec4(const unsigned* p) {
    unsigned r;
    asm volatile("global_load_dword %0, %1, off sc0 sc1\n\t"
                 "s_waitcnt vmcnt(0)"
                 : "=v"(r) : "v"(p) : "memory");
    return r;
}
__device__ __forceinline__ void store_rec4(unsigned* p, unsigned v) {
    asm volatile("global_store_dword %0, %1, off sc0 sc1"
                 :: "v"(p), "v"(v) : "memory");
}

// ---------------------------------------------------------------------------
// w1t[c*4096 + r] = (int8) w1[r*700 + c]
__global__ __launch_bounds__(256) void k_transpose_i8(
    const int* __restrict__ in, signed char* __restrict__ out,
    int R, int C, int out_stride)
{
    __shared__ signed char tile[32][33];
    const int cx = blockIdx.x * 32;
    const int ry = blockIdx.y * 32;
    const int tx = threadIdx.x;
    const int ty = threadIdx.y;
#pragma unroll
    for (int r = 0; r < 4; ++r) {
        int row = ry + ty + r * 8;
        int col = cx + tx;
        if (row < R && col < C)
            tile[ty + r * 8][tx] = (signed char)in[(size_t)row * C + col];
    }
    __syncthreads();
#pragma unroll
    for (int r = 0; r < 4; ++r) {
        int c   = cx + ty + r * 8;
        int row = ry + tx;
        if (c < C && row < R)
            out[(size_t)c * out_stride + row] = tile[tx][ty + r * 8];
    }
}

// ---------------------------------------------------------------------------
// v1n[b][k] = 8B row: 16 nibbles = (v1[b*16+j][k] + 8), j=0..15
__global__ __launch_bounds__(256) void k_prep_v1n(
    const int* __restrict__ in, unsigned char* __restrict__ out)
{
    __shared__ unsigned char tile[16][64];
    const int k0 = blockIdx.x * 64;
    const int b  = blockIdx.y;
    const int t  = threadIdx.x;
    const int kk = t & 63;
#pragma unroll
    for (int r = 0; r < 4; ++r) {
        int hl = (t >> 6) + r * 4;     // 0..15
        tile[hl][kk] = (unsigned char)(in[(size_t)(b * NPB + hl) * N_HID + k0 + kk] + 8);
    }
    __syncthreads();
    if (t < 64) {
        unsigned w0 = 0, w1 = 0;
#pragma unroll
        for (int j = 0; j < 8; ++j) w0 |= (unsigned)tile[j][t] << (4 * j);
#pragma unroll
        for (int j = 0; j < 8; ++j) w1 |= (unsigned)tile[8 + j][t] << (4 * j);
        u32x2 v = {w0, w1};
        *(u32x2*)(out + ((size_t)b << 15) + ((size_t)(k0 + t) << 3)) = v;
    }
}

// ---------------------------------------------------------------------------
// in_all2[b][t][16]: in_all2[(h>>4)*T*16 + t*16 + (h&15)]
__global__ __launch_bounds__(256) void k_inall(
    const signed char* __restrict__ w1t,   // [N_IN][N_HID]
    const int* __restrict__ spk,           // [T][N_IN]
    short* __restrict__ in_all2)           // [256][T][16]
{
    __shared__ int s_spk[16][N_IN];
    const int t0 = blockIdx.y * 16;
    const int tcnt = min(16, T_STEPS - t0);
    const int tid = threadIdx.x;
    for (int b = 0; b < tcnt; ++b)
        for (int i = tid; i < N_IN; i += 256)
            s_spk[b][i] = spk[(size_t)(t0 + b) * N_IN + i];
    __syncthreads();
    const int h = blockIdx.x * 256 + tid;
    int acc[16];
#pragma unroll
    for (int b = 0; b < 16; ++b) acc[b] = 0;
    for (int i = 0; i < N_IN; ++i) {
        int w = (int)w1t[(size_t)i * N_HID + h];
#pragma unroll
        for (int b = 0; b < 16; ++b) acc[b] += w * s_spk[b][i];
    }
    const size_t base = (size_t)(h >> 4) * (T_STEPS * NPB) + (h & 15);
    for (int b = 0; b < tcnt; ++b)
        in_all2[base + (size_t)(t0 + b) * NPB] = (short)acc[b];
}

// ---------------------------------------------------------------------------
// Main LIF loop: 256 blocks x 1 wave x 16 neurons. Whole weight slice (32KB,
// nibble-packed) in LDS. No barriers. pub[r] = 0x10000|mask16(out(r)),
// published at top of iter r-1 (1.5-iter lead); row t prefetched via
// global_load_lds (1KB = 64 lanes x 16B), drained by vmcnt(0) at next top.
// Lane L owns k-range [64L, 64L+64) = records 4L..4L+3. Lanes 16-63 mirror
// lanes 0-15's neuron state (same in_cur/fb), so ballot low 16 bits = mask.
__global__ __launch_bounds__(64) void k_main(
    const short* __restrict__ in_all2,      // [256][T][16]
    const u32x2* __restrict__ v1n,          // [256][4096] 8B nibble rows
    unsigned* __restrict__ pub)             // [T+1][256], zeroed
{
    const int lane = threadIdx.x;
    const int bid  = blockIdx.x;
    const int j    = lane & 15;             // mirrored neuron index

    __shared__ u32x2 s_w[N_HID];            // 32KB weight slice
    __shared__ u32x4 s_rec[2][64];          // double-buffered record rows, 2KB

    // ---- load weight slice once (coalesced 8B x 64 lanes per iter) ----
    {
        const u32x2* src = v1n + ((size_t)bid << 12);
        for (int r = lane; r < N_HID; r += 64) s_w[r] = src[r];
    }
    asm volatile("s_waitcnt vmcnt(0) lgkmcnt(0)" ::: "memory");

    if (lane == 0) store_rec4(pub + bid, 0x10000u);   // row 0: out(0)=0

    // lookahead state: mm = m'(t), synv = syn(t-1), out_t = out(t)
    int mm = 0, synv = 0, out_t = 0;
    const short* in_base = in_all2 + (size_t)bid * (T_STEPS * NPB) + j;
    const u32x2* wl = s_w + (lane << 6);
    const unsigned NM = 0x000F000Fu;

    for (int t = 0; t < T_STEPS; ++t) {
        const int cur = t & 1;
        // drain prev iter's prefetch (and store/in_cur; all >=1 iter old)
        asm volatile("s_waitcnt vmcnt(0)" ::: "memory");
        __builtin_amdgcn_sched_barrier(0);

        // ---- publish out(t+1) from local state ----
        int mem_t = (mm - (mm >> 3)) + synv;
        int mnext = out_t ? 0 : mem_t;
        int out_n = (mnext - 1 > 0) ? 1 : 0;
        unsigned om = (unsigned)__ballot(out_n) & 0xFFFFu;
        if (lane == 0) store_rec4(pub + (size_t)(t + 1) * NBLK + bid, 0x10000u | om);
        mm = mnext; out_t = out_n;

        int in_cur = (int)in_base[t * NPB];

        // ---- prefetch row t (for iter t+1): 64 lanes x 16B = 1KB ----
        __builtin_amdgcn_global_load_lds(
            (const void*)(pub + (size_t)t * NBLK + (lane << 2)),
            (void*)&s_rec[cur ^ 1][0], 16, 0, /*sc0|sc1*/ 17);

        // ---- consume row t-1: this lane's 4 records -> 64-bit k-mask ----
        unsigned mlo = 0, mhi = 0;
        if (t > 0) {
            u32x4 q = s_rec[cur][lane];
            if (((q.x & q.y & q.z & q.w) & 0x10000u) == 0u) {   // straggler
                const unsigned* rp = pub + (size_t)(t - 1) * NBLK + (lane << 2);
                while (!(q.x & 0x10000u)) { __builtin_amdgcn_s_sleep(1); q.x = load_rec4(rp + 0); }
                while (!(q.y & 0x10000u)) { __builtin_amdgcn_s_sleep(1); q.y = load_rec4(rp + 1); }
                while (!(q.z & 0x10000u)) { __builtin_amdgcn_s_sleep(1); q.z = load_rec4(rp + 2); }
                while (!(q.w & 0x10000u)) { __builtin_amdgcn_s_sleep(1); q.w = load_rec4(rp + 3); }
            }
            mlo = (q.x & 0xFFFFu) | ((q.y & 0xFFFFu) << 16);
            mhi = (q.z & 0xFFFFu) | ((q.w & 0xFFFFu) << 16);
        }
        unsigned long long m = ((unsigned long long)mhi << 32) | mlo;
        int myc = __popcll(m);

        // ---- gather over set bits: 4-deep double-buffered LDS pipeline ----
        unsigned a0=0,a1=0,a2=0,a3=0,a4=0,a5=0,a6=0,a7=0;
#define ACC(v) do { \
            a0 += (v).x & NM;         a1 += ((v).x >> 4)  & NM; \
            a2 += ((v).x >> 8) & NM;  a3 += ((v).x >> 12) & NM; \
            a4 += (v).y & NM;         a5 += ((v).y >> 4)  & NM; \
            a6 += ((v).y >> 8) & NM;  a7 += ((v).y >> 12) & NM; } while (0)
        u32x2 p0={0,0}, p1={0,0}, p2={0,0}, p3={0,0};
        int b;
        if (m) { b = __builtin_ctzll(m); m &= m - 1; p0 = wl[b]; }
        if (m) { b = __builtin_ctzll(m); m &= m - 1; p1 = wl[b]; }
        if (m) { b = __builtin_ctzll(m); m &= m - 1; p2 = wl[b]; }
        if (m) { b = __builtin_ctzll(m); m &= m - 1; p3 = wl[b]; }
        while (m) {
            u32x2 n0={0,0}, n1={0,0}, n2={0,0}, n3={0,0};
            if (m) { b = __builtin_ctzll(m); m &= m - 1; n0 = wl[b]; }
            if (m) { b = __builtin_ctzll(m); m &= m - 1; n1 = wl[b]; }
            if (m) { b = __builtin_ctzll(m); m &= m - 1; n2 = wl[b]; }
            if (m) { b = __builtin_ctzll(m); m &= m - 1; n3 = wl[b]; }
            ACC(p0); ACC(p1); ACC(p2); ACC(p3);
            p0 = n0; p1 = n1; p2 = n2; p3 = n3;
        }
        ACC(p0); ACC(p1); ACC(p2); ACC(p3);
#undef ACC

        // ---- reduce across 64 lanes (k-partials) + spike count ----
#pragma unroll
        for (int s = 1; s <= 32; s <<= 1) {
            a0 += __shfl_xor(a0, s); a1 += __shfl_xor(a1, s);
            a2 += __shfl_xor(a2, s); a3 += __shfl_xor(a3, s);
            a4 += __shfl_xor(a4, s); a5 += __shfl_xor(a5, s);
            a6 += __shfl_xor(a6, s); a7 += __shfl_xor(a7, s);
            myc += __shfl_xor(myc, s);
        }

        // ---- select this lane's neuron field: reg=(j&3)|((j&8)>>1), half=(j>>2)&1
        unsigned g0 = (j & 1) ? a1 : a0, g1 = (j & 1) ? a3 : a2;
        unsigned g2 = (j & 1) ? a5 : a4, g3 = (j & 1) ? a7 : a6;
        unsigned h0 = (j & 2) ? g1 : g0, h1 = (j & 2) ? g3 : g2;
        unsigned sel = (j & 8) ? h1 : h0;
        int field = (j & 4) ? (int)(sel >> 16) : (int)(sel & 0xFFFFu);
        int fb = field - 8 * myc;

        synv = (synv - (synv >> 4)) + in_cur + fb;   // syn(t)
    }
}

// ---------------------------------------------------------------------------
// ro[t][o] = sum_{k in spikes(t)} w2[o][k]; records: 0x10000|mask16
__global__ __launch_bounds__(256) void k_rocur(
    const int* __restrict__ w2,                // [N_OUT][N_HID]
    const unsigned* __restrict__ pub,
    int* __restrict__ ro)                      // [T][N_OUT]
{
    const int t = blockIdx.x;
    const int tid = threadIdx.x;
    __shared__ unsigned short s_list[N_HID];
    __shared__ int s_red[32][8];
    __shared__ int s_n;
    if (tid < 64) {
        const unsigned* rp = pub + (size_t)t * NBLK + (tid << 2);
        unsigned long long m =
            (unsigned long long)((rp[0] & 0xFFFFu) | ((rp[1] & 0xFFFFu) << 16)) |
            ((unsigned long long)((rp[2] & 0xFFFFu) | ((rp[3] & 0xFFFFu) << 16)) << 32);
        int cnt = __popcll(m);
        int inc = cnt;
#pragma unroll
        for (int d = 1; d < 64; d <<= 1) {
            int v = __shfl_up(inc, d);
            if (tid >= d) inc += v;
        }
        int p = inc - cnt;
        while (m) {
            s_list[p++] = (unsigned short)((tid << 6) | __builtin_ctzll(m));
            m &= m - 1;
        }
        if (tid == 63) s_n = inc;
    }
    __syncthreads();
    const int n = s_n;
    const int o = tid >> 3;
    const int r = tid & 7;
    if (o < N_OUT) {
        int acc = 0;
        for (int jj = r; jj < n; jj += 8) acc += w2[(size_t)o * N_HID + s_list[jj]];
        s_red[o][r] = acc;
    }
    __syncthreads();
    if (tid < N_OUT) {
        int acc = 0;
#pragma unroll
        for (int q = 0; q < 8; ++q) acc += s_red[tid][q];
        ro[(size_t)t * N_OUT + tid] = acc;
    }
}

// ---------------------------------------------------------------------------
// readout LIF scan; LDS-staged reads + coalesced stores. out [N_OUT][T] int32.
#define CH 250
__global__ __launch_bounds__(256) void k_scan(const int* __restrict__ ro,
                                              int* __restrict__ out)
{
    __shared__ int s_ro[CH * N_OUT];
    __shared__ int s_out[CH * N_OUT];
    const int tid = threadIdx.x;
    int rm = 0, rs = 0;
    for (int c = 0; c < T_STEPS / CH; ++c) {
        for (int i = tid; i < CH * N_OUT; i += 256)
            s_ro[i] = ro[c * CH * N_OUT + i];
        __syncthreads();
        if (tid < N_OUT) {
            for (int jj = 0; jj < CH; ++jj) {
                rm = (rm - (rm >> 3)) + rs;
                rs = (rs - (rs >> 4)) + s_ro[jj * N_OUT + tid];
                s_out[jj * N_OUT + tid] = rm;
            }
        }
        __syncthreads();
        for (int i = tid; i < CH * N_OUT; i += 256) {
            int o = i / CH, jj = i - o * CH;
            out[o * T_STEPS + c * CH + jj] = s_out[jj * N_OUT + o];
        }
        __syncthreads();
    }
}

// ---------------------------------------------------------------------------
extern "C" void kernel_launch(void* const* d_in, const int* in_sizes, int n_in,
                              void* d_out, int out_size, void* d_ws, size_t ws_size,
                              hipStream_t stream)
{
    const int* spk = (const int*)d_in[0];   // [1000][700]
    const int* w1  = (const int*)d_in[1];   // [4096][700]
    const int* v1  = (const int*)d_in[2];   // [4096][4096]
    const int* w2  = (const int*)d_in[3];   // [20][4096]
    int* out = (int*)d_out;                 // [20][1000] int32

    char* ws = (char*)d_ws;
    constexpr size_t SZ_PUB    = (size_t)(T_STEPS + 1) * NBLK * 4;  // 1,025,024
    constexpr size_t OFF_PUB   = 0;
    constexpr size_t OFF_INALL = OFF_PUB + SZ_PUB;                  // 8,192,000
    constexpr size_t OFF_V1N   = OFF_INALL + 8192000;               // 8,388,608
    constexpr size_t OFF_W1T   = OFF_V1N + 8388608;                 // 2,867,200
    constexpr size_t OFF_RO    = OFF_W1T + 2867200;                 // 80,000

    unsigned*       pub    = (unsigned*)(ws + OFF_PUB);
    short*          in_all = (short*)(ws + OFF_INALL);
    unsigned char*  v1n    = (unsigned char*)(ws + OFF_V1N);
    signed char*    w1t    = (signed char*)(ws + OFF_W1T);
    int*            ro     = (int*)(ws + OFF_RO);

    hipMemsetAsync(pub, 0, SZ_PUB, stream);   // clear flags (graph replays)

    dim3 tb(32, 8);
    k_prep_v1n<<<dim3(64, 256), 256, 0, stream>>>(v1, v1n);
    k_transpose_i8<<<dim3(22, 128), tb, 0, stream>>>(w1, w1t, N_HID, N_IN, N_HID);
    k_inall<<<dim3(16, 63), 256, 0, stream>>>(w1t, spk, in_all);

    k_main<<<dim3(NBLK), dim3(64), 0, stream>>>(in_all, (const u32x2*)v1n, pub);

    k_rocur<<<dim3(T_STEPS), 256, 0, stream>>>(w2, pub, ro);
    k_scan<<<1, 256, 0, stream>>>(ro, out);
}